// Round 11
// baseline (283.350 us; speedup 1.0000x reference)
//
#include <hip/hip_runtime.h>
#include <float.h>

// B=4, S=2048, D=1024, H=16, hd=64. bf16 MFMA pipeline:
//   prep (fused: cast_x + transpose_cast(w_qkv) + transpose_cast(w_out))
//   gemm_qkv / gemm_out: 128x128 tile, BK=64, TRIPLE-buffered LDS with
//     distance-2 global_load_lds prefetch + counted vmcnt(8) (never 0
//     mid-loop) + raw barrier. Tile kt+2 issued at step kt -> ~2 K-steps
//     (~800 cyc) of latency slack vs 1 step for the __syncthreads dbuf.
//   attn (MFMA flash, 64-row Q tiles, complementary-pair blocks, bh-major
//     grid for XCD-L2 locality, K/V double-buffered prefetch)

#define SEQ   2048
#define DIM   1024
#define NH    16
#define HD    64
#define MROWS 8192
#define BHTOT 64

// prep kernel block ranges
#define PREP_CAST_BLOCKS  8192              // 8192*1024 elems / 1024 per block
#define PREP_WQKV_BLOCKS  3072              // (1024/32)*(3072/32)
#define PREP_WOUT_BLOCKS  1024              // (1024/32)*(1024/32)

typedef __bf16 bf16_t;
typedef __bf16 bf16x4 __attribute__((ext_vector_type(4)));
typedef __bf16 bf16x8 __attribute__((ext_vector_type(8)));
typedef float  f32x4  __attribute__((ext_vector_type(4)));

typedef const __attribute__((address_space(1))) unsigned int* gas_ptr;
typedef __attribute__((address_space(3))) unsigned int* las_ptr;

__device__ __forceinline__ void gll16(const bf16_t* g, bf16_t* l) {
    __builtin_amdgcn_global_load_lds((gas_ptr)g, (las_ptr)l, 16, 0, 0);
}

// ---------------- fused prep kernel ----------------
// blocks [0, 8192): cast x fp32 -> bf16 (1024 elems/block)
// blocks [8192, 11264): transpose_cast w_qkv [1024][3072] -> wqkvT [3072][1024]
// blocks [11264, 12288): transpose_cast w_out [1024][1024] -> woutT [1024][1024]
__global__ __launch_bounds__(256) void prep_kernel(
    const float* __restrict__ x,     bf16_t* __restrict__ xb,
    const float* __restrict__ w_qkv, bf16_t* __restrict__ wqkvT,
    const float* __restrict__ w_out, bf16_t* __restrict__ woutT)
{
    __shared__ float t[32][33];
    const int blk = blockIdx.x;

    if (blk < PREP_CAST_BLOCKS) {
        int i = (blk * 256 + threadIdx.x) * 4;
        float4 v = *(const float4*)(x + i);
        bf16x4 o = { (bf16_t)v.x, (bf16_t)v.y, (bf16_t)v.z, (bf16_t)v.w };
        *(bf16x4*)(xb + i) = o;
        return;
    }

    const float* w;  bf16_t* wT;  int N, tile;
    if (blk < PREP_CAST_BLOCKS + PREP_WQKV_BLOCKS) {
        tile = blk - PREP_CAST_BLOCKS;  w = w_qkv;  wT = wqkvT;  N = 3 * DIM;
    } else {
        tile = blk - PREP_CAST_BLOCKS - PREP_WQKV_BLOCKS;  w = w_out;  wT = woutT;  N = DIM;
    }
    const int bk = (tile & 31) * 32;         // K tile (DIM/32 = 32 tiles)
    const int bn = (tile >> 5) * 32;         // N tile
    const int r = threadIdx.x >> 5, c = threadIdx.x & 31;
    #pragma unroll
    for (int i = 0; i < 4; i++)
        t[r + i * 8][c] = w[(size_t)(bk + r + i * 8) * N + bn + c];
    __syncthreads();
    #pragma unroll
    for (int i = 0; i < 4; i++)
        wT[(size_t)(bn + r + i * 8) * DIM + bk + c] = (bf16_t)t[c][r + i * 8];
}

// ======== GEMM main loop: 128x128, BK=64, 3-buf distance-2 pipeline ========
// Step kt: (1) s_waitcnt vmcnt(8) -- own tile-kt gll16 writes complete (the 8
// newest in flight are tile kt+1's); vmcnt(0) only at kt=15. (2) raw barrier
// (sched_barrier-fenced) -- ALL waves' tile-kt writes landed + prior readers
// of the stage target are done. (3) issue tile kt+2's 8 gll16 into buffer
// (kt+2)%3 (post-barrier => WAR-safe vs step kt-1's readers). (4) frag-read
// buf kt%3 + 32 MFMA. Each tile gets ~2 K-steps of load latency slack.
// LDS 96 KiB -> 1 block/CU; latency hiding comes from the pipeline.
__device__ __forceinline__ void gemm_pipe3_compute(
    const bf16_t* __restrict__ Ag, const bf16_t* __restrict__ Bg,
    int bm, int bn, bf16_t* As, bf16_t* Bs, f32x4 (&acc)[4][4])
{
    const int tid = threadIdx.x;
    const int lane = tid & 63, w = tid >> 6;
    const int quad = lane >> 4, l16 = lane & 15;
    const int wr = w >> 1, wc = w & 1;

    auto stage = [&](int kt, int buf) {
        const int k0 = kt * 64;
        bf16_t* Ad = As + buf * (128 * 64);
        bf16_t* Bd = Bs + buf * (128 * 64);
        #pragma unroll
        for (int p = 0; p < 4; p++) {
            int flat = p * 256 + tid;
            int row = flat >> 3, g = flat & 7, gs = g ^ (row & 7);
            gll16(Ag + (size_t)(bm + row) * DIM + k0 + gs * 8,
                  Ad + (size_t)(p * 256 + w * 64) * 8);
            gll16(Bg + (size_t)(bn + row) * DIM + k0 + gs * 8,
                  Bd + (size_t)(p * 256 + w * 64) * 8);
        }
    };

    // prologue: tiles 0 and 1 in flight (16 loads/thread outstanding)
    stage(0, 0);
    stage(1, 1);

    #pragma unroll 1
    for (int kt = 0; kt < 16; kt++) {
        // (1) own tile-kt writes landed (8 newest = tile kt+1 stay in flight)
        if (kt < 15) asm volatile("s_waitcnt vmcnt(8)" ::: "memory");
        else         asm volatile("s_waitcnt vmcnt(0)" ::: "memory");
        // (2) rendezvous: all waves' tile-kt writes visible; prior readers done
        __builtin_amdgcn_sched_barrier(0);
        __builtin_amdgcn_s_barrier();
        __builtin_amdgcn_sched_barrier(0);
        asm volatile("" ::: "memory");
        // (3) distance-2 prefetch into the buffer freed at step kt-1
        if (kt + 2 < 16) stage(kt + 2, (kt + 2) % 3);

        // (4) compute on buf kt%3
        const bf16_t* Ac = As + (kt % 3) * (128 * 64);
        const bf16_t* Bc = Bs + (kt % 3) * (128 * 64);
        #pragma unroll
        for (int ks = 0; ks < 2; ks++) {
            bf16x8 af[4], bfv[4];
            #pragma unroll
            for (int mt = 0; mt < 4; mt++) {
                int row = wr * 64 + mt * 16 + l16;
                int g = (ks * 4 + quad) ^ (row & 7);
                af[mt] = *(const bf16x8*)(Ac + row * 64 + g * 8);
            }
            #pragma unroll
            for (int nt = 0; nt < 4; nt++) {
                int row = wc * 64 + nt * 16 + l16;
                int g = (ks * 4 + quad) ^ (row & 7);
                bfv[nt] = *(const bf16x8*)(Bc + row * 64 + g * 8);
            }
            #pragma unroll
            for (int mt = 0; mt < 4; mt++)
                #pragma unroll
                for (int nt = 0; nt < 4; nt++)
                    acc[mt][nt] = __builtin_amdgcn_mfma_f32_16x16x32_bf16(
                        af[mt], bfv[nt], acc[mt][nt], 0, 0, 0);
        }
    }
}

__global__ __launch_bounds__(256) void gemm_qkv_kernel(
    const bf16_t* __restrict__ Ag,   // [8192][1024]
    const bf16_t* __restrict__ Bg,   // [3072][1024]
    bf16_t* __restrict__ qN, bf16_t* __restrict__ kN, bf16_t* __restrict__ vT)
{
    __shared__ __align__(16) bf16_t As[3 * 128 * 64];
    __shared__ __align__(16) bf16_t Bs[3 * 128 * 64];
    const int tid = threadIdx.x;
    const int lane = tid & 63, w = tid >> 6;
    const int quad = lane >> 4, l16 = lane & 15;
    const int wr = w >> 1, wc = w & 1;
    const int bm = blockIdx.x * 128, bn = blockIdx.y * 128;

    f32x4 acc[4][4] = {};
    gemm_pipe3_compute(Ag, Bg, bm, bn, As, Bs, acc);

    const int which = bn >> 10;   // 0=q, 1=k, 2=v (uniform per block)
    if (which == 2) {
        #pragma unroll
        for (int mt = 0; mt < 4; mt++)
            #pragma unroll
            for (int nt = 0; nt < 4; nt++) {
                int row0 = bm + wr * 64 + mt * 16 + quad * 4;
                int b = row0 >> 11, s0 = row0 & 2047;
                int col = bn + wc * 64 + nt * 16 + l16;
                int nn = col & 1023, h = nn >> 6, d = nn & 63;
                int bh = b * NH + h;
                bf16x4 vv;
                #pragma unroll
                for (int r = 0; r < 4; r++) vv[r] = (bf16_t)acc[mt][nt][r];
                *(bf16x4*)(vT + ((size_t)bh * HD + d) * SEQ + s0) = vv;
            }
    } else {
        const float qsc = (which == 0) ? 0.18033688011112042f : 1.0f; // (1/8)*log2(e)
        bf16_t* dst = (which == 0) ? qN : kN;
        #pragma unroll
        for (int mt = 0; mt < 4; mt++)
            #pragma unroll
            for (int nt = 0; nt < 4; nt++)
                #pragma unroll
                for (int r = 0; r < 4; r++) {
                    int row = bm + wr * 64 + mt * 16 + quad * 4 + r;
                    int b = row >> 11, s = row & 2047;
                    int col = bn + wc * 64 + nt * 16 + l16;
                    int nn = col & 1023, h = nn >> 6, d = nn & 63;
                    int bh = b * NH + h;
                    dst[((size_t)bh * SEQ + s) * HD + d] = (bf16_t)(acc[mt][nt][r] * qsc);
                }
    }
}

__global__ __launch_bounds__(256) void gemm_out_kernel(
    const bf16_t* __restrict__ Ag,   // attnb [8192][1024]
    const bf16_t* __restrict__ Bg,   // woutT [1024][1024]
    float* __restrict__ out)
{
    __shared__ __align__(16) bf16_t As[3 * 128 * 64];
    __shared__ __align__(16) bf16_t Bs[3 * 128 * 64];
    const int tid = threadIdx.x;
    const int lane = tid & 63, w = tid >> 6;
    const int quad = lane >> 4, l16 = lane & 15;
    const int wr = w >> 1, wc = w & 1;
    const int bm = blockIdx.x * 128, bn = blockIdx.y * 128;

    f32x4 acc[4][4] = {};
    gemm_pipe3_compute(Ag, Bg, bm, bn, As, Bs, acc);

    #pragma unroll
    for (int mt = 0; mt < 4; mt++)
        #pragma unroll
        for (int nt = 0; nt < 4; nt++)
            #pragma unroll
            for (int r = 0; r < 4; r++) {
                int row = bm + wr * 64 + mt * 16 + quad * 4 + r;
                int col = bn + wc * 64 + nt * 16 + l16;
                out[(size_t)row * DIM + col] = acc[mt][nt][r];
            }
}

// ---------------- MFMA flash attention, S^T orientation ----------------
// grid (64, 16): x = bh (FASTEST-varying), y = pair index. Flat block id =
// y*64 + x, so id % 8 = bh % 8: all 16 pair-blocks of one bh land on ONE
// XCD -> its 4 MiB L2 holds that XCD's 8 bh x 512 KB K/V working set and
// absorbs the 16x K/V re-reads. Block processes q-tiles {t, 31-t}
// sequentially -> 33 kt-iterations for EVERY block. 40 KB LDS -> 4
// blocks/CU (16 waves). Wave w owns q-rows [w*16, w*16+16).
// S^T = K·Q^T (operand swap); P^T stored XOR-granule-swizzled (stride 64,
// aliasing dead Q tile); O^T = V^T·P^T. K/V double-buffered prefetch.
__global__ __launch_bounds__(256) void attn_kernel(
    const bf16_t* __restrict__ qN, const bf16_t* __restrict__ kN,
    const bf16_t* __restrict__ vT, bf16_t* __restrict__ attnb)
{
    __shared__ __align__(16) char smem[40960];
    bf16_t* QPs = (bf16_t*)smem;             // 8 KB: Q tile 64x64, later P^T 64x64 swizzled
    bf16_t* Ks  = (bf16_t*)(smem + 8192);    // [2][key][d] swizzled, 2 x 8 KB
    bf16_t* Vs  = (bf16_t*)(smem + 24576);   // [2][d][key] swizzled, 2 x 8 KB

    const int bh = blockIdx.x;               // bh fastest -> same-XCD per bh
    const int pr = blockIdx.y;               // pair index 0..15
    const int tid = threadIdx.x;
    const int lane = tid & 63, w = tid >> 6;
    const int quad = lane >> 4, l16 = lane & 15;

    const bf16_t* qbase = qN + (size_t)bh * SEQ * HD;
    const bf16_t* kbase = kN + (size_t)bh * SEQ * HD;
    const bf16_t* vbase = vT + (size_t)bh * HD * SEQ;
    const int b = bh >> 4, h = bh & 15;

    // stage K/V tile kt into buffer buf (all 256 threads; 2 gll16 each)
    auto stage_kv = [&](int kt, int buf) {
        bf16_t* Kd = Ks + buf * 4096;
        bf16_t* Vd = Vs + buf * 4096;
        #pragma unroll
        for (int p = 0; p < 2; p++) {
            int flat = p * 256 + tid;
            int row = flat >> 3, g = flat & 7;
            int gs = g ^ (row & 7);
            gll16(kbase + (size_t)(kt * 64 + row) * HD + gs * 8, Kd + (size_t)(p * 256 + w * 64) * 8);
            gll16(vbase + (size_t)row * SEQ + kt * 64 + gs * 8,  Vd + (size_t)(p * 256 + w * 64) * 8);
        }
    };

    #pragma unroll 1
    for (int phase = 0; phase < 2; phase++) {
        const int t = (phase == 0) ? pr : 31 - pr;

        __syncthreads();   // phase 1: prior phase's LDS readers done
        // stage Q tile t (64 rows x 64), XOR-granule swizzle
        #pragma unroll
        for (int p = 0; p < 2; p++) {
            int flat = p * 256 + tid;
            int row = flat >> 3, g = flat & 7;
            int gs = g ^ (row & 7);
            gll16(qbase + (size_t)(t * 64 + row) * HD + gs * 8,
                  QPs + (size_t)(p * 256 + w * 64) * 8);
        }
        stage_kv(0, 0);
        __syncthreads();   // drains all global_load_lds

        bf16x8 qa[2];      // B-operand fragments: n = qrow
        #pragma unroll
        for (int ks = 0; ks < 2; ks++) {
            int row = w * 16 + l16;
            int g = (ks * 4 + quad) ^ (row & 7);
            qa[ks] = *(const bf16x8*)(QPs + row * 64 + g * 8);
        }

        f32x4 o[4] = {};   // O^T: rows d = dt*16+quad*4+r, col qrow = w*16+l16
        float l_part = 0.0f;

        const int rl = w * 16 + l16;          // local q-row of this lane
        const int qrow = t * 64 + rl;

        for (int kt = 0; kt <= t; kt++) {
            const int cur = kt & 1;
            // issue next-tile loads; drain at end-of-iteration barrier
            if (kt < t) stage_kv(kt + 1, cur ^ 1);

            const bf16_t* Kc = Ks + cur * 4096;
            const bf16_t* Vc = Vs + cur * 4096;

            // ---- S^T = K Q^T : D[key][qrow]; key = kt*64+nt*16+quad*4+r ----
            f32x4 s[4] = {};
            #pragma unroll
            for (int ks = 0; ks < 2; ks++) {
                bf16x8 kb[4];
                #pragma unroll
                for (int nt = 0; nt < 4; nt++) {
                    int row = nt * 16 + l16;
                    int g = (ks * 4 + quad) ^ (row & 7);
                    kb[nt] = *(const bf16x8*)(Kc + row * 64 + g * 8);
                }
                #pragma unroll
                for (int nt = 0; nt < 4; nt++)
                    s[nt] = __builtin_amdgcn_mfma_f32_16x16x32_bf16(
                        kb[nt], qa[ks], s[nt], 0, 0, 0);
            }

            // ---- p = exp2(s) (Q pre-scaled), accumulate l, swizzled P^T store ----
            const bool maskit = (kt == t);
            #pragma unroll
            for (int nt = 0; nt < 4; nt++) {
                bf16x4 pk;
                #pragma unroll
                for (int r = 0; r < 4; r++) {
                    float pv;
                    if (maskit) {
                        int key = kt * 64 + nt * 16 + quad * 4 + r;
                        pv = (key <= qrow) ? __builtin_amdgcn_exp2f(s[nt][r]) : 0.0f;
                    } else {
                        pv = __builtin_amdgcn_exp2f(s[nt][r]);
                    }
                    l_part += pv;
                    pk[r] = (bf16_t)pv;
                }
                // P^T[rl][key], XOR-granule swizzle (same-wave rows only)
                int gs = (nt * 2 + (quad >> 1)) ^ (rl & 7);
                *(bf16x4*)(QPs + rl * 64 + gs * 8 + (quad & 1) * 4) = pk;
            }

            // ---- O^T += V^T P^T ----
            #pragma unroll
            for (int ks = 0; ks < 2; ks++) {
                bf16x8 vb[4], pb;
                #pragma unroll
                for (int dt = 0; dt < 4; dt++) {
                    int row = dt * 16 + l16;
                    int g = (ks * 4 + quad) ^ (row & 7);
                    vb[dt] = *(const bf16x8*)(Vc + row * 64 + g * 8);
                }
                {
                    int g = (ks * 4 + quad) ^ (rl & 7);
                    pb = *(const bf16x8*)(QPs + rl * 64 + g * 8);
                }
                #pragma unroll
                for (int dt = 0; dt < 4; dt++)
                    o[dt] = __builtin_amdgcn_mfma_f32_16x16x32_bf16(
                        vb[dt], pb, o[dt], 0, 0, 0);
            }

            __syncthreads();   // readers of buf 'cur' done + prefetch drained
        }

        // ---- epilogue: reduce l across quads (lanes l16,+16,+32,+48 share qrow) ----
        float lsum = l_part;
        lsum += __shfl_xor(lsum, 16, 64);
        lsum += __shfl_xor(lsum, 32, 64);
        float inv = 1.0f / lsum;
        const int srow = t * 64 + w * 16 + l16;
        #pragma unroll
        for (int dt = 0; dt < 4; dt++) {
            bf16x4 ov;
            #pragma unroll
            for (int r = 0; r < 4; r++) ov[r] = (bf16_t)(o[dt][r] * inv);
            *(bf16x4*)(attnb + ((size_t)(b * SEQ + srow)) * DIM + h * HD + dt * 16 + quad * 4) = ov;
        }
    }
}

extern "C" void kernel_launch(void* const* d_in, const int* in_sizes, int n_in,
                              void* d_out, int out_size, void* d_ws, size_t ws_size,
                              hipStream_t stream) {
    const float* x     = (const float*)d_in[0];
    const float* w_qkv = (const float*)d_in[1];
    const float* w_out = (const float*)d_in[2];
    float* out = (float*)d_out;

    bf16_t* xb    = (bf16_t*)d_ws;                          // 8192*1024
    bf16_t* wqkvT = xb    + (size_t)MROWS * DIM;            // 3072*1024
    bf16_t* woutT = wqkvT + (size_t)3 * DIM * DIM;          // 1024*1024
    bf16_t* qNb   = woutT + (size_t)DIM * DIM;              // 64*2048*64
    bf16_t* kNb   = qNb   + (size_t)BHTOT * SEQ * HD;
    bf16_t* vTb   = kNb   + (size_t)BHTOT * SEQ * HD;
    bf16_t* attnb = vTb   + (size_t)BHTOT * SEQ * HD;       // 8192*1024

    prep_kernel<<<PREP_CAST_BLOCKS + PREP_WQKV_BLOCKS + PREP_WOUT_BLOCKS, 256, 0, stream>>>(
        x, xb, w_qkv, wqkvT, w_out, woutT);
    gemm_qkv_kernel<<<dim3(MROWS / 128, 3 * DIM / 128), 256, 0, stream>>>(xb, wqkvT, qNb, kNb, vTb);
    attn_kernel<<<dim3(BHTOT, 16), 256, 0, stream>>>(qNb, kNb, vTb, attnb);
    gemm_out_kernel<<<dim3(MROWS / 128, DIM / 128), 256, 0, stream>>>(attnb, woutT, out);
}

// Round 12
// 228.763 us; speedup vs baseline: 1.2386x; 1.2386x over previous
//
#include <hip/hip_runtime.h>
#include <float.h>

// B=4, S=2048, D=1024, H=16, hd=64. bf16 MFMA pipeline:
//   prep (fused: cast_x + transpose_cast(w_qkv) + transpose_cast(w_out))
//   gemm_qkv / gemm_out: 128x128 tile, BK=64, double-buffered LDS with
//     prefetch-before-compute, ONE __syncthreads per K-tile (round-9 verified
//     best: 66 us gemm_qkv, 2 blocks/CU) + T5 setprio around MFMA clusters
//   attn (MFMA flash, 64-row Q tiles, complementary-pair blocks, bh-major
//     grid for XCD-L2 locality, K/V double-buffered prefetch, T5 setprio)

#define SEQ   2048
#define DIM   1024
#define NH    16
#define HD    64
#define MROWS 8192
#define BHTOT 64

// prep kernel block ranges
#define PREP_CAST_BLOCKS  8192              // 8192*1024 elems / 1024 per block
#define PREP_WQKV_BLOCKS  3072              // (1024/32)*(3072/32)
#define PREP_WOUT_BLOCKS  1024              // (1024/32)*(1024/32)

typedef __bf16 bf16_t;
typedef __bf16 bf16x4 __attribute__((ext_vector_type(4)));
typedef __bf16 bf16x8 __attribute__((ext_vector_type(8)));
typedef float  f32x4  __attribute__((ext_vector_type(4)));

typedef const __attribute__((address_space(1))) unsigned int* gas_ptr;
typedef __attribute__((address_space(3))) unsigned int* las_ptr;

__device__ __forceinline__ void gll16(const bf16_t* g, bf16_t* l) {
    __builtin_amdgcn_global_load_lds((gas_ptr)g, (las_ptr)l, 16, 0, 0);
}

// ---------------- fused prep kernel ----------------
// blocks [0, 8192): cast x fp32 -> bf16 (1024 elems/block)
// blocks [8192, 11264): transpose_cast w_qkv [1024][3072] -> wqkvT [3072][1024]
// blocks [11264, 12288): transpose_cast w_out [1024][1024] -> woutT [1024][1024]
__global__ __launch_bounds__(256) void prep_kernel(
    const float* __restrict__ x,     bf16_t* __restrict__ xb,
    const float* __restrict__ w_qkv, bf16_t* __restrict__ wqkvT,
    const float* __restrict__ w_out, bf16_t* __restrict__ woutT)
{
    __shared__ float t[32][33];
    const int blk = blockIdx.x;

    if (blk < PREP_CAST_BLOCKS) {
        int i = (blk * 256 + threadIdx.x) * 4;
        float4 v = *(const float4*)(x + i);
        bf16x4 o = { (bf16_t)v.x, (bf16_t)v.y, (bf16_t)v.z, (bf16_t)v.w };
        *(bf16x4*)(xb + i) = o;
        return;
    }

    const float* w;  bf16_t* wT;  int N, tile;
    if (blk < PREP_CAST_BLOCKS + PREP_WQKV_BLOCKS) {
        tile = blk - PREP_CAST_BLOCKS;  w = w_qkv;  wT = wqkvT;  N = 3 * DIM;
    } else {
        tile = blk - PREP_CAST_BLOCKS - PREP_WQKV_BLOCKS;  w = w_out;  wT = woutT;  N = DIM;
    }
    const int bk = (tile & 31) * 32;         // K tile (DIM/32 = 32 tiles)
    const int bn = (tile >> 5) * 32;         // N tile
    const int r = threadIdx.x >> 5, c = threadIdx.x & 31;
    #pragma unroll
    for (int i = 0; i < 4; i++)
        t[r + i * 8][c] = w[(size_t)(bk + r + i * 8) * N + bn + c];
    __syncthreads();
    #pragma unroll
    for (int i = 0; i < 4; i++)
        wT[(size_t)(bn + r + i * 8) * DIM + bk + c] = (bf16_t)t[c][r + i * 8];
}

// ======== GEMM main loop: 128x128, BK=64, double-buffered prefetch ========
// (round-9 verified structure: 66 us gemm_qkv, 2 blocks/CU, 8 waves/CU;
//  independent blocks cover each other's barrier-drain stalls)
// Per K-tile: issue next tile's 8 gll16 into the other buffer FIRST, then
// frag-read + 32 MFMA on current buffer, then one __syncthreads (drains the
// prefetch AND fences readers). T5: setprio(1) around the MFMA cluster so
// the scheduler favors the MFMA-issuing block over the staging block.
__device__ __forceinline__ void gemm_dbuf_compute(
    const bf16_t* __restrict__ Ag, const bf16_t* __restrict__ Bg,
    int bm, int bn, bf16_t* As, bf16_t* Bs, f32x4 (&acc)[4][4])
{
    const int tid = threadIdx.x;
    const int lane = tid & 63, w = tid >> 6;
    const int quad = lane >> 4, l16 = lane & 15;
    const int wr = w >> 1, wc = w & 1;

    auto stage = [&](int kt, int buf) {
        const int k0 = kt * 64;
        bf16_t* Ad = As + buf * (128 * 64);
        bf16_t* Bd = Bs + buf * (128 * 64);
        #pragma unroll
        for (int p = 0; p < 4; p++) {
            int flat = p * 256 + tid;
            int row = flat >> 3, g = flat & 7, gs = g ^ (row & 7);
            gll16(Ag + (size_t)(bm + row) * DIM + k0 + gs * 8,
                  Ad + (size_t)(p * 256 + w * 64) * 8);
            gll16(Bg + (size_t)(bn + row) * DIM + k0 + gs * 8,
                  Bd + (size_t)(p * 256 + w * 64) * 8);
        }
    };

    stage(0, 0);
    __syncthreads();

    #pragma unroll 1
    for (int kt = 0; kt < 16; kt++) {
        const int cur = kt & 1;
        if (kt < 15) stage(kt + 1, cur ^ 1);
        const bf16_t* Ac = As + cur * (128 * 64);
        const bf16_t* Bc = Bs + cur * (128 * 64);
        #pragma unroll
        for (int ks = 0; ks < 2; ks++) {
            bf16x8 af[4], bfv[4];
            #pragma unroll
            for (int mt = 0; mt < 4; mt++) {
                int row = wr * 64 + mt * 16 + l16;
                int g = (ks * 4 + quad) ^ (row & 7);
                af[mt] = *(const bf16x8*)(Ac + row * 64 + g * 8);
            }
            #pragma unroll
            for (int nt = 0; nt < 4; nt++) {
                int row = wc * 64 + nt * 16 + l16;
                int g = (ks * 4 + quad) ^ (row & 7);
                bfv[nt] = *(const bf16x8*)(Bc + row * 64 + g * 8);
            }
            __builtin_amdgcn_s_setprio(1);
            #pragma unroll
            for (int mt = 0; mt < 4; mt++)
                #pragma unroll
                for (int nt = 0; nt < 4; nt++)
                    acc[mt][nt] = __builtin_amdgcn_mfma_f32_16x16x32_bf16(
                        af[mt], bfv[nt], acc[mt][nt], 0, 0, 0);
            __builtin_amdgcn_s_setprio(0);
        }
        __syncthreads();
    }
}

__global__ __launch_bounds__(256) void gemm_qkv_kernel(
    const bf16_t* __restrict__ Ag,   // [8192][1024]
    const bf16_t* __restrict__ Bg,   // [3072][1024]
    bf16_t* __restrict__ qN, bf16_t* __restrict__ kN, bf16_t* __restrict__ vT)
{
    __shared__ __align__(16) bf16_t As[2 * 128 * 64];
    __shared__ __align__(16) bf16_t Bs[2 * 128 * 64];
    const int tid = threadIdx.x;
    const int lane = tid & 63, w = tid >> 6;
    const int quad = lane >> 4, l16 = lane & 15;
    const int wr = w >> 1, wc = w & 1;
    const int bm = blockIdx.x * 128, bn = blockIdx.y * 128;

    f32x4 acc[4][4] = {};
    gemm_dbuf_compute(Ag, Bg, bm, bn, As, Bs, acc);

    const int which = bn >> 10;   // 0=q, 1=k, 2=v (uniform per block)
    if (which == 2) {
        #pragma unroll
        for (int mt = 0; mt < 4; mt++)
            #pragma unroll
            for (int nt = 0; nt < 4; nt++) {
                int row0 = bm + wr * 64 + mt * 16 + quad * 4;
                int b = row0 >> 11, s0 = row0 & 2047;
                int col = bn + wc * 64 + nt * 16 + l16;
                int nn = col & 1023, h = nn >> 6, d = nn & 63;
                int bh = b * NH + h;
                bf16x4 vv;
                #pragma unroll
                for (int r = 0; r < 4; r++) vv[r] = (bf16_t)acc[mt][nt][r];
                *(bf16x4*)(vT + ((size_t)bh * HD + d) * SEQ + s0) = vv;
            }
    } else {
        const float qsc = (which == 0) ? 0.18033688011112042f : 1.0f; // (1/8)*log2(e)
        bf16_t* dst = (which == 0) ? qN : kN;
        #pragma unroll
        for (int mt = 0; mt < 4; mt++)
            #pragma unroll
            for (int nt = 0; nt < 4; nt++)
                #pragma unroll
                for (int r = 0; r < 4; r++) {
                    int row = bm + wr * 64 + mt * 16 + quad * 4 + r;
                    int b = row >> 11, s = row & 2047;
                    int col = bn + wc * 64 + nt * 16 + l16;
                    int nn = col & 1023, h = nn >> 6, d = nn & 63;
                    int bh = b * NH + h;
                    dst[((size_t)bh * SEQ + s) * HD + d] = (bf16_t)(acc[mt][nt][r] * qsc);
                }
    }
}

__global__ __launch_bounds__(256) void gemm_out_kernel(
    const bf16_t* __restrict__ Ag,   // attnb [8192][1024]
    const bf16_t* __restrict__ Bg,   // woutT [1024][1024]
    float* __restrict__ out)
{
    __shared__ __align__(16) bf16_t As[2 * 128 * 64];
    __shared__ __align__(16) bf16_t Bs[2 * 128 * 64];
    const int tid = threadIdx.x;
    const int lane = tid & 63, w = tid >> 6;
    const int quad = lane >> 4, l16 = lane & 15;
    const int wr = w >> 1, wc = w & 1;
    const int bm = blockIdx.x * 128, bn = blockIdx.y * 128;

    f32x4 acc[4][4] = {};
    gemm_dbuf_compute(Ag, Bg, bm, bn, As, Bs, acc);

    #pragma unroll
    for (int mt = 0; mt < 4; mt++)
        #pragma unroll
        for (int nt = 0; nt < 4; nt++)
            #pragma unroll
            for (int r = 0; r < 4; r++) {
                int row = bm + wr * 64 + mt * 16 + quad * 4 + r;
                int col = bn + wc * 64 + nt * 16 + l16;
                out[(size_t)row * DIM + col] = acc[mt][nt][r];
            }
}

// ---------------- MFMA flash attention, S^T orientation ----------------
// grid (64, 16): x = bh (FASTEST-varying), y = pair index. Flat block id =
// y*64 + x, so id % 8 = bh % 8: all 16 pair-blocks of one bh land on ONE
// XCD -> its 4 MiB L2 holds that XCD's 8 bh x 512 KB K/V working set and
// absorbs the 16x K/V re-reads. Block processes q-tiles {t, 31-t}
// sequentially -> 33 kt-iterations for EVERY block. 40 KB LDS -> 4
// blocks/CU (16 waves). Wave w owns q-rows [w*16, w*16+16).
// S^T = K·Q^T (operand swap); P^T stored XOR-granule-swizzled (stride 64,
// aliasing dead Q tile); O^T = V^T·P^T. K/V double-buffered prefetch.
// T5: setprio(1) around MFMA clusters (m191: +4-7% with independent blocks).
__global__ __launch_bounds__(256) void attn_kernel(
    const bf16_t* __restrict__ qN, const bf16_t* __restrict__ kN,
    const bf16_t* __restrict__ vT, bf16_t* __restrict__ attnb)
{
    __shared__ __align__(16) char smem[40960];
    bf16_t* QPs = (bf16_t*)smem;             // 8 KB: Q tile 64x64, later P^T 64x64 swizzled
    bf16_t* Ks  = (bf16_t*)(smem + 8192);    // [2][key][d] swizzled, 2 x 8 KB
    bf16_t* Vs  = (bf16_t*)(smem + 24576);   // [2][d][key] swizzled, 2 x 8 KB

    const int bh = blockIdx.x;               // bh fastest -> same-XCD per bh
    const int pr = blockIdx.y;               // pair index 0..15
    const int tid = threadIdx.x;
    const int lane = tid & 63, w = tid >> 6;
    const int quad = lane >> 4, l16 = lane & 15;

    const bf16_t* qbase = qN + (size_t)bh * SEQ * HD;
    const bf16_t* kbase = kN + (size_t)bh * SEQ * HD;
    const bf16_t* vbase = vT + (size_t)bh * HD * SEQ;
    const int b = bh >> 4, h = bh & 15;

    // stage K/V tile kt into buffer buf (all 256 threads; 2 gll16 each)
    auto stage_kv = [&](int kt, int buf) {
        bf16_t* Kd = Ks + buf * 4096;
        bf16_t* Vd = Vs + buf * 4096;
        #pragma unroll
        for (int p = 0; p < 2; p++) {
            int flat = p * 256 + tid;
            int row = flat >> 3, g = flat & 7;
            int gs = g ^ (row & 7);
            gll16(kbase + (size_t)(kt * 64 + row) * HD + gs * 8, Kd + (size_t)(p * 256 + w * 64) * 8);
            gll16(vbase + (size_t)row * SEQ + kt * 64 + gs * 8,  Vd + (size_t)(p * 256 + w * 64) * 8);
        }
    };

    #pragma unroll 1
    for (int phase = 0; phase < 2; phase++) {
        const int t = (phase == 0) ? pr : 31 - pr;

        __syncthreads();   // phase 1: prior phase's LDS readers done
        // stage Q tile t (64 rows x 64), XOR-granule swizzle
        #pragma unroll
        for (int p = 0; p < 2; p++) {
            int flat = p * 256 + tid;
            int row = flat >> 3, g = flat & 7;
            int gs = g ^ (row & 7);
            gll16(qbase + (size_t)(t * 64 + row) * HD + gs * 8,
                  QPs + (size_t)(p * 256 + w * 64) * 8);
        }
        stage_kv(0, 0);
        __syncthreads();   // drains all global_load_lds

        bf16x8 qa[2];      // B-operand fragments: n = qrow
        #pragma unroll
        for (int ks = 0; ks < 2; ks++) {
            int row = w * 16 + l16;
            int g = (ks * 4 + quad) ^ (row & 7);
            qa[ks] = *(const bf16x8*)(QPs + row * 64 + g * 8);
        }

        f32x4 o[4] = {};   // O^T: rows d = dt*16+quad*4+r, col qrow = w*16+l16
        float l_part = 0.0f;

        const int rl = w * 16 + l16;          // local q-row of this lane
        const int qrow = t * 64 + rl;

        for (int kt = 0; kt <= t; kt++) {
            const int cur = kt & 1;
            // issue next-tile loads; drain at end-of-iteration barrier
            if (kt < t) stage_kv(kt + 1, cur ^ 1);

            const bf16_t* Kc = Ks + cur * 4096;
            const bf16_t* Vc = Vs + cur * 4096;

            // ---- S^T = K Q^T : D[key][qrow]; key = kt*64+nt*16+quad*4+r ----
            f32x4 s[4] = {};
            #pragma unroll
            for (int ks = 0; ks < 2; ks++) {
                bf16x8 kb[4];
                #pragma unroll
                for (int nt = 0; nt < 4; nt++) {
                    int row = nt * 16 + l16;
                    int g = (ks * 4 + quad) ^ (row & 7);
                    kb[nt] = *(const bf16x8*)(Kc + row * 64 + g * 8);
                }
                __builtin_amdgcn_s_setprio(1);
                #pragma unroll
                for (int nt = 0; nt < 4; nt++)
                    s[nt] = __builtin_amdgcn_mfma_f32_16x16x32_bf16(
                        kb[nt], qa[ks], s[nt], 0, 0, 0);
                __builtin_amdgcn_s_setprio(0);
            }

            // ---- p = exp2(s) (Q pre-scaled), accumulate l, swizzled P^T store ----
            const bool maskit = (kt == t);
            #pragma unroll
            for (int nt = 0; nt < 4; nt++) {
                bf16x4 pk;
                #pragma unroll
                for (int r = 0; r < 4; r++) {
                    float pv;
                    if (maskit) {
                        int key = kt * 64 + nt * 16 + quad * 4 + r;
                        pv = (key <= qrow) ? __builtin_amdgcn_exp2f(s[nt][r]) : 0.0f;
                    } else {
                        pv = __builtin_amdgcn_exp2f(s[nt][r]);
                    }
                    l_part += pv;
                    pk[r] = (bf16_t)pv;
                }
                // P^T[rl][key], XOR-granule swizzle (same-wave rows only)
                int gs = (nt * 2 + (quad >> 1)) ^ (rl & 7);
                *(bf16x4*)(QPs + rl * 64 + gs * 8 + (quad & 1) * 4) = pk;
            }

            // ---- O^T += V^T P^T ----
            #pragma unroll
            for (int ks = 0; ks < 2; ks++) {
                bf16x8 vb[4], pb;
                #pragma unroll
                for (int dt = 0; dt < 4; dt++) {
                    int row = dt * 16 + l16;
                    int g = (ks * 4 + quad) ^ (row & 7);
                    vb[dt] = *(const bf16x8*)(Vc + row * 64 + g * 8);
                }
                {
                    int g = (ks * 4 + quad) ^ (rl & 7);
                    pb = *(const bf16x8*)(QPs + rl * 64 + g * 8);
                }
                __builtin_amdgcn_s_setprio(1);
                #pragma unroll
                for (int dt = 0; dt < 4; dt++)
                    o[dt] = __builtin_amdgcn_mfma_f32_16x16x32_bf16(
                        vb[dt], pb, o[dt], 0, 0, 0);
                __builtin_amdgcn_s_setprio(0);
            }

            __syncthreads();   // readers of buf 'cur' done + prefetch drained
        }

        // ---- epilogue: reduce l across quads (lanes l16,+16,+32,+48 share qrow) ----
        float lsum = l_part;
        lsum += __shfl_xor(lsum, 16, 64);
        lsum += __shfl_xor(lsum, 32, 64);
        float inv = 1.0f / lsum;
        const int srow = t * 64 + w * 16 + l16;
        #pragma unroll
        for (int dt = 0; dt < 4; dt++) {
            bf16x4 ov;
            #pragma unroll
            for (int r = 0; r < 4; r++) ov[r] = (bf16_t)(o[dt][r] * inv);
            *(bf16x4*)(attnb + ((size_t)(b * SEQ + srow)) * DIM + h * HD + dt * 16 + quad * 4) = ov;
        }
    }
}

extern "C" void kernel_launch(void* const* d_in, const int* in_sizes, int n_in,
                              void* d_out, int out_size, void* d_ws, size_t ws_size,
                              hipStream_t stream) {
    const float* x     = (const float*)d_in[0];
    const float* w_qkv = (const float*)d_in[1];
    const float* w_out = (const float*)d_in[2];
    float* out = (float*)d_out;

    bf16_t* xb    = (bf16_t*)d_ws;                          // 8192*1024
    bf16_t* wqkvT = xb    + (size_t)MROWS * DIM;            // 3072*1024
    bf16_t* woutT = wqkvT + (size_t)3 * DIM * DIM;          // 1024*1024
    bf16_t* qNb   = woutT + (size_t)DIM * DIM;              // 64*2048*64
    bf16_t* kNb   = qNb   + (size_t)BHTOT * SEQ * HD;
    bf16_t* vTb   = kNb   + (size_t)BHTOT * SEQ * HD;
    bf16_t* attnb = vTb   + (size_t)BHTOT * SEQ * HD;       // 8192*1024

    prep_kernel<<<PREP_CAST_BLOCKS + PREP_WQKV_BLOCKS + PREP_WOUT_BLOCKS, 256, 0, stream>>>(
        x, xb, w_qkv, wqkvT, w_out, woutT);
    gemm_qkv_kernel<<<dim3(MROWS / 128, 3 * DIM / 128), 256, 0, stream>>>(xb, wqkvT, qNb, kNb, vTb);
    attn_kernel<<<dim3(BHTOT, 16), 256, 0, stream>>>(qNb, kNb, vTb, attnb);
    gemm_out_kernel<<<dim3(MROWS / 128, DIM / 128), 256, 0, stream>>>(attnb, woutT, out);
}

// Round 13
// 226.091 us; speedup vs baseline: 1.2533x; 1.0118x over previous
//
#include <hip/hip_runtime.h>
#include <float.h>

// B=4, S=2048, D=1024, H=16, hd=64. bf16 MFMA pipeline:
//   prep (fused: cast_x + transpose_cast(w_qkv) + transpose_cast(w_out))
//   gemm_qkv / gemm_out: 128x128 tile, BK=64, SINGLE 32 KiB LDS buffer
//     (m97-style sync;stage;sync;compute) -> 5 blocks/CU: independent blocks
//     cover each other's vmcnt-drain stalls (TLP at fixed BK=64 quantum)
//   attn (MFMA flash, 64-row Q tiles, complementary-pair blocks, bh-major
//     grid for XCD-L2 locality, K/V double-buffered prefetch, T5 setprio)

#define SEQ   2048
#define DIM   1024
#define NH    16
#define HD    64
#define MROWS 8192
#define BHTOT 64

// prep kernel block ranges
#define PREP_CAST_BLOCKS  8192              // 8192*1024 elems / 1024 per block
#define PREP_WQKV_BLOCKS  3072              // (1024/32)*(3072/32)
#define PREP_WOUT_BLOCKS  1024              // (1024/32)*(1024/32)

typedef __bf16 bf16_t;
typedef __bf16 bf16x4 __attribute__((ext_vector_type(4)));
typedef __bf16 bf16x8 __attribute__((ext_vector_type(8)));
typedef float  f32x4  __attribute__((ext_vector_type(4)));

typedef const __attribute__((address_space(1))) unsigned int* gas_ptr;
typedef __attribute__((address_space(3))) unsigned int* las_ptr;

__device__ __forceinline__ void gll16(const bf16_t* g, bf16_t* l) {
    __builtin_amdgcn_global_load_lds((gas_ptr)g, (las_ptr)l, 16, 0, 0);
}

// ---------------- fused prep kernel ----------------
// blocks [0, 8192): cast x fp32 -> bf16 (1024 elems/block)
// blocks [8192, 11264): transpose_cast w_qkv [1024][3072] -> wqkvT [3072][1024]
// blocks [11264, 12288): transpose_cast w_out [1024][1024] -> woutT [1024][1024]
__global__ __launch_bounds__(256) void prep_kernel(
    const float* __restrict__ x,     bf16_t* __restrict__ xb,
    const float* __restrict__ w_qkv, bf16_t* __restrict__ wqkvT,
    const float* __restrict__ w_out, bf16_t* __restrict__ woutT)
{
    __shared__ float t[32][33];
    const int blk = blockIdx.x;

    if (blk < PREP_CAST_BLOCKS) {
        int i = (blk * 256 + threadIdx.x) * 4;
        float4 v = *(const float4*)(x + i);
        bf16x4 o = { (bf16_t)v.x, (bf16_t)v.y, (bf16_t)v.z, (bf16_t)v.w };
        *(bf16x4*)(xb + i) = o;
        return;
    }

    const float* w;  bf16_t* wT;  int N, tile;
    if (blk < PREP_CAST_BLOCKS + PREP_WQKV_BLOCKS) {
        tile = blk - PREP_CAST_BLOCKS;  w = w_qkv;  wT = wqkvT;  N = 3 * DIM;
    } else {
        tile = blk - PREP_CAST_BLOCKS - PREP_WQKV_BLOCKS;  w = w_out;  wT = woutT;  N = DIM;
    }
    const int bk = (tile & 31) * 32;         // K tile (DIM/32 = 32 tiles)
    const int bn = (tile >> 5) * 32;         // N tile
    const int r = threadIdx.x >> 5, c = threadIdx.x & 31;
    #pragma unroll
    for (int i = 0; i < 4; i++)
        t[r + i * 8][c] = w[(size_t)(bk + r + i * 8) * N + bn + c];
    __syncthreads();
    #pragma unroll
    for (int i = 0; i < 4; i++)
        wT[(size_t)(bn + r + i * 8) * DIM + bk + c] = (bf16_t)t[c][r + i * 8];
}

// ======== GEMM main loop: 128x128, BK=64, single-buffer, 5 blocks/CU ======
// m97-style: per K-step { __syncthreads (prior readers done); stage 8 gll16;
// __syncthreads (drains loads); 32 MFMA }. Per-block the drain is exposed,
// but 32 KiB LDS + 88 VGPR -> 5 resident blocks/CU whose phases interleave:
// while one block drains, four compute. T5 setprio biases the scheduler
// toward MFMA-issuing blocks.
__device__ __forceinline__ void gemm_sbuf_compute(
    const bf16_t* __restrict__ Ag, const bf16_t* __restrict__ Bg,
    int bm, int bn, bf16_t* As, bf16_t* Bs, f32x4 (&acc)[4][4])
{
    const int tid = threadIdx.x;
    const int lane = tid & 63, w = tid >> 6;
    const int quad = lane >> 4, l16 = lane & 15;
    const int wr = w >> 1, wc = w & 1;

    auto stage = [&](int kt) {
        const int k0 = kt * 64;
        #pragma unroll
        for (int p = 0; p < 4; p++) {
            int flat = p * 256 + tid;
            int row = flat >> 3, g = flat & 7, gs = g ^ (row & 7);
            gll16(Ag + (size_t)(bm + row) * DIM + k0 + gs * 8,
                  As + (size_t)(p * 256 + w * 64) * 8);
            gll16(Bg + (size_t)(bn + row) * DIM + k0 + gs * 8,
                  Bs + (size_t)(p * 256 + w * 64) * 8);
        }
    };

    #pragma unroll 1
    for (int kt = 0; kt < 16; kt++) {
        __syncthreads();                 // prior step's readers done
        stage(kt);
        __syncthreads();                 // drain: tile kt resident
        #pragma unroll
        for (int ks = 0; ks < 2; ks++) {
            bf16x8 af[4], bfv[4];
            #pragma unroll
            for (int mt = 0; mt < 4; mt++) {
                int row = wr * 64 + mt * 16 + l16;
                int g = (ks * 4 + quad) ^ (row & 7);
                af[mt] = *(const bf16x8*)(As + row * 64 + g * 8);
            }
            #pragma unroll
            for (int nt = 0; nt < 4; nt++) {
                int row = wc * 64 + nt * 16 + l16;
                int g = (ks * 4 + quad) ^ (row & 7);
                bfv[nt] = *(const bf16x8*)(Bs + row * 64 + g * 8);
            }
            __builtin_amdgcn_s_setprio(1);
            #pragma unroll
            for (int mt = 0; mt < 4; mt++)
                #pragma unroll
                for (int nt = 0; nt < 4; nt++)
                    acc[mt][nt] = __builtin_amdgcn_mfma_f32_16x16x32_bf16(
                        af[mt], bfv[nt], acc[mt][nt], 0, 0, 0);
            __builtin_amdgcn_s_setprio(0);
        }
    }
}

__global__ __launch_bounds__(256) void gemm_qkv_kernel(
    const bf16_t* __restrict__ Ag,   // [8192][1024]
    const bf16_t* __restrict__ Bg,   // [3072][1024]
    bf16_t* __restrict__ qN, bf16_t* __restrict__ kN, bf16_t* __restrict__ vT)
{
    __shared__ __align__(16) bf16_t As[128 * 64];
    __shared__ __align__(16) bf16_t Bs[128 * 64];
    const int tid = threadIdx.x;
    const int lane = tid & 63, w = tid >> 6;
    const int quad = lane >> 4, l16 = lane & 15;
    const int wr = w >> 1, wc = w & 1;
    const int bm = blockIdx.x * 128, bn = blockIdx.y * 128;

    f32x4 acc[4][4] = {};
    gemm_sbuf_compute(Ag, Bg, bm, bn, As, Bs, acc);

    const int which = bn >> 10;   // 0=q, 1=k, 2=v (uniform per block)
    if (which == 2) {
        #pragma unroll
        for (int mt = 0; mt < 4; mt++)
            #pragma unroll
            for (int nt = 0; nt < 4; nt++) {
                int row0 = bm + wr * 64 + mt * 16 + quad * 4;
                int b = row0 >> 11, s0 = row0 & 2047;
                int col = bn + wc * 64 + nt * 16 + l16;
                int nn = col & 1023, h = nn >> 6, d = nn & 63;
                int bh = b * NH + h;
                bf16x4 vv;
                #pragma unroll
                for (int r = 0; r < 4; r++) vv[r] = (bf16_t)acc[mt][nt][r];
                *(bf16x4*)(vT + ((size_t)bh * HD + d) * SEQ + s0) = vv;
            }
    } else {
        const float qsc = (which == 0) ? 0.18033688011112042f : 1.0f; // (1/8)*log2(e)
        bf16_t* dst = (which == 0) ? qN : kN;
        #pragma unroll
        for (int mt = 0; mt < 4; mt++)
            #pragma unroll
            for (int nt = 0; nt < 4; nt++)
                #pragma unroll
                for (int r = 0; r < 4; r++) {
                    int row = bm + wr * 64 + mt * 16 + quad * 4 + r;
                    int b = row >> 11, s = row & 2047;
                    int col = bn + wc * 64 + nt * 16 + l16;
                    int nn = col & 1023, h = nn >> 6, d = nn & 63;
                    int bh = b * NH + h;
                    dst[((size_t)bh * SEQ + s) * HD + d] = (bf16_t)(acc[mt][nt][r] * qsc);
                }
    }
}

__global__ __launch_bounds__(256) void gemm_out_kernel(
    const bf16_t* __restrict__ Ag,   // attnb [8192][1024]
    const bf16_t* __restrict__ Bg,   // woutT [1024][1024]
    float* __restrict__ out)
{
    __shared__ __align__(16) bf16_t As[128 * 64];
    __shared__ __align__(16) bf16_t Bs[128 * 64];
    const int tid = threadIdx.x;
    const int lane = tid & 63, w = tid >> 6;
    const int quad = lane >> 4, l16 = lane & 15;
    const int wr = w >> 1, wc = w & 1;
    const int bm = blockIdx.x * 128, bn = blockIdx.y * 128;

    f32x4 acc[4][4] = {};
    gemm_sbuf_compute(Ag, Bg, bm, bn, As, Bs, acc);

    #pragma unroll
    for (int mt = 0; mt < 4; mt++)
        #pragma unroll
        for (int nt = 0; nt < 4; nt++)
            #pragma unroll
            for (int r = 0; r < 4; r++) {
                int row = bm + wr * 64 + mt * 16 + quad * 4 + r;
                int col = bn + wc * 64 + nt * 16 + l16;
                out[(size_t)row * DIM + col] = acc[mt][nt][r];
            }
}

// ---------------- MFMA flash attention, S^T orientation ----------------
// grid (64, 16): x = bh (FASTEST-varying), y = pair index. Flat block id =
// y*64 + x, so id % 8 = bh % 8: all 16 pair-blocks of one bh land on ONE
// XCD -> its 4 MiB L2 holds that XCD's 8 bh x 512 KB K/V working set and
// absorbs the 16x K/V re-reads. Block processes q-tiles {t, 31-t}
// sequentially -> 33 kt-iterations for EVERY block. 40 KB LDS -> 4
// blocks/CU (16 waves). Wave w owns q-rows [w*16, w*16+16).
// S^T = K·Q^T (operand swap); P^T stored XOR-granule-swizzled (stride 64,
// aliasing dead Q tile); O^T = V^T·P^T. K/V double-buffered prefetch.
// T5: setprio(1) around MFMA clusters.
__global__ __launch_bounds__(256) void attn_kernel(
    const bf16_t* __restrict__ qN, const bf16_t* __restrict__ kN,
    const bf16_t* __restrict__ vT, bf16_t* __restrict__ attnb)
{
    __shared__ __align__(16) char smem[40960];
    bf16_t* QPs = (bf16_t*)smem;             // 8 KB: Q tile 64x64, later P^T 64x64 swizzled
    bf16_t* Ks  = (bf16_t*)(smem + 8192);    // [2][key][d] swizzled, 2 x 8 KB
    bf16_t* Vs  = (bf16_t*)(smem + 24576);   // [2][d][key] swizzled, 2 x 8 KB

    const int bh = blockIdx.x;               // bh fastest -> same-XCD per bh
    const int pr = blockIdx.y;               // pair index 0..15
    const int tid = threadIdx.x;
    const int lane = tid & 63, w = tid >> 6;
    const int quad = lane >> 4, l16 = lane & 15;

    const bf16_t* qbase = qN + (size_t)bh * SEQ * HD;
    const bf16_t* kbase = kN + (size_t)bh * SEQ * HD;
    const bf16_t* vbase = vT + (size_t)bh * HD * SEQ;
    const int b = bh >> 4, h = bh & 15;

    // stage K/V tile kt into buffer buf (all 256 threads; 2 gll16 each)
    auto stage_kv = [&](int kt, int buf) {
        bf16_t* Kd = Ks + buf * 4096;
        bf16_t* Vd = Vs + buf * 4096;
        #pragma unroll
        for (int p = 0; p < 2; p++) {
            int flat = p * 256 + tid;
            int row = flat >> 3, g = flat & 7;
            int gs = g ^ (row & 7);
            gll16(kbase + (size_t)(kt * 64 + row) * HD + gs * 8, Kd + (size_t)(p * 256 + w * 64) * 8);
            gll16(vbase + (size_t)row * SEQ + kt * 64 + gs * 8,  Vd + (size_t)(p * 256 + w * 64) * 8);
        }
    };

    #pragma unroll 1
    for (int phase = 0; phase < 2; phase++) {
        const int t = (phase == 0) ? pr : 31 - pr;

        __syncthreads();   // phase 1: prior phase's LDS readers done
        // stage Q tile t (64 rows x 64), XOR-granule swizzle
        #pragma unroll
        for (int p = 0; p < 2; p++) {
            int flat = p * 256 + tid;
            int row = flat >> 3, g = flat & 7;
            int gs = g ^ (row & 7);
            gll16(qbase + (size_t)(t * 64 + row) * HD + gs * 8,
                  QPs + (size_t)(p * 256 + w * 64) * 8);
        }
        stage_kv(0, 0);
        __syncthreads();   // drains all global_load_lds

        bf16x8 qa[2];      // B-operand fragments: n = qrow
        #pragma unroll
        for (int ks = 0; ks < 2; ks++) {
            int row = w * 16 + l16;
            int g = (ks * 4 + quad) ^ (row & 7);
            qa[ks] = *(const bf16x8*)(QPs + row * 64 + g * 8);
        }

        f32x4 o[4] = {};   // O^T: rows d = dt*16+quad*4+r, col qrow = w*16+l16
        float l_part = 0.0f;

        const int rl = w * 16 + l16;          // local q-row of this lane
        const int qrow = t * 64 + rl;

        for (int kt = 0; kt <= t; kt++) {
            const int cur = kt & 1;
            // issue next-tile loads; drain at end-of-iteration barrier
            if (kt < t) stage_kv(kt + 1, cur ^ 1);

            const bf16_t* Kc = Ks + cur * 4096;
            const bf16_t* Vc = Vs + cur * 4096;

            // ---- S^T = K Q^T : D[key][qrow]; key = kt*64+nt*16+quad*4+r ----
            f32x4 s[4] = {};
            #pragma unroll
            for (int ks = 0; ks < 2; ks++) {
                bf16x8 kb[4];
                #pragma unroll
                for (int nt = 0; nt < 4; nt++) {
                    int row = nt * 16 + l16;
                    int g = (ks * 4 + quad) ^ (row & 7);
                    kb[nt] = *(const bf16x8*)(Kc + row * 64 + g * 8);
                }
                __builtin_amdgcn_s_setprio(1);
                #pragma unroll
                for (int nt = 0; nt < 4; nt++)
                    s[nt] = __builtin_amdgcn_mfma_f32_16x16x32_bf16(
                        kb[nt], qa[ks], s[nt], 0, 0, 0);
                __builtin_amdgcn_s_setprio(0);
            }

            // ---- p = exp2(s) (Q pre-scaled), accumulate l, swizzled P^T store ----
            const bool maskit = (kt == t);
            #pragma unroll
            for (int nt = 0; nt < 4; nt++) {
                bf16x4 pk;
                #pragma unroll
                for (int r = 0; r < 4; r++) {
                    float pv;
                    if (maskit) {
                        int key = kt * 64 + nt * 16 + quad * 4 + r;
                        pv = (key <= qrow) ? __builtin_amdgcn_exp2f(s[nt][r]) : 0.0f;
                    } else {
                        pv = __builtin_amdgcn_exp2f(s[nt][r]);
                    }
                    l_part += pv;
                    pk[r] = (bf16_t)pv;
                }
                // P^T[rl][key], XOR-granule swizzle (same-wave rows only)
                int gs = (nt * 2 + (quad >> 1)) ^ (rl & 7);
                *(bf16x4*)(QPs + rl * 64 + gs * 8 + (quad & 1) * 4) = pk;
            }

            // ---- O^T += V^T P^T ----
            #pragma unroll
            for (int ks = 0; ks < 2; ks++) {
                bf16x8 vb[4], pb;
                #pragma unroll
                for (int dt = 0; dt < 4; dt++) {
                    int row = dt * 16 + l16;
                    int g = (ks * 4 + quad) ^ (row & 7);
                    vb[dt] = *(const bf16x8*)(Vc + row * 64 + g * 8);
                }
                {
                    int g = (ks * 4 + quad) ^ (rl & 7);
                    pb = *(const bf16x8*)(QPs + rl * 64 + g * 8);
                }
                __builtin_amdgcn_s_setprio(1);
                #pragma unroll
                for (int dt = 0; dt < 4; dt++)
                    o[dt] = __builtin_amdgcn_mfma_f32_16x16x32_bf16(
                        vb[dt], pb, o[dt], 0, 0, 0);
                __builtin_amdgcn_s_setprio(0);
            }

            __syncthreads();   // readers of buf 'cur' done + prefetch drained
        }

        // ---- epilogue: reduce l across quads (lanes l16,+16,+32,+48 share qrow) ----
        float lsum = l_part;
        lsum += __shfl_xor(lsum, 16, 64);
        lsum += __shfl_xor(lsum, 32, 64);
        float inv = 1.0f / lsum;
        const int srow = t * 64 + w * 16 + l16;
        #pragma unroll
        for (int dt = 0; dt < 4; dt++) {
            bf16x4 ov;
            #pragma unroll
            for (int r = 0; r < 4; r++) ov[r] = (bf16_t)(o[dt][r] * inv);
            *(bf16x4*)(attnb + ((size_t)(b * SEQ + srow)) * DIM + h * HD + dt * 16 + quad * 4) = ov;
        }
    }
}

extern "C" void kernel_launch(void* const* d_in, const int* in_sizes, int n_in,
                              void* d_out, int out_size, void* d_ws, size_t ws_size,
                              hipStream_t stream) {
    const float* x     = (const float*)d_in[0];
    const float* w_qkv = (const float*)d_in[1];
    const float* w_out = (const float*)d_in[2];
    float* out = (float*)d_out;

    bf16_t* xb    = (bf16_t*)d_ws;                          // 8192*1024
    bf16_t* wqkvT = xb    + (size_t)MROWS * DIM;            // 3072*1024
    bf16_t* woutT = wqkvT + (size_t)3 * DIM * DIM;          // 1024*1024
    bf16_t* qNb   = woutT + (size_t)DIM * DIM;              // 64*2048*64
    bf16_t* kNb   = qNb   + (size_t)BHTOT * SEQ * HD;
    bf16_t* vTb   = kNb   + (size_t)BHTOT * SEQ * HD;
    bf16_t* attnb = vTb   + (size_t)BHTOT * SEQ * HD;       // 8192*1024

    prep_kernel<<<PREP_CAST_BLOCKS + PREP_WQKV_BLOCKS + PREP_WOUT_BLOCKS, 256, 0, stream>>>(
        x, xb, w_qkv, wqkvT, w_out, woutT);
    gemm_qkv_kernel<<<dim3(MROWS / 128, 3 * DIM / 128), 256, 0, stream>>>(xb, wqkvT, qNb, kNb, vTb);
    attn_kernel<<<dim3(BHTOT, 16), 256, 0, stream>>>(qNb, kNb, vTb, attnb);
    gemm_out_kernel<<<dim3(MROWS / 128, DIM / 128), 256, 0, stream>>>(attnb, woutT, out);
}